// Round 1
// baseline (967.179 us; speedup 1.0000x reference)
//
#include <hip/hip_runtime.h>

#define NATOMS 100000
#define ADIM 12
#define RDIM 1024
#define FDIM 128
#define KNB 10

#define BM 128
#define BK 64
#define LDST 72          // LDS row stride in bf16 elems (64 + 8 pad)
#define KT_RES 16        // 1024 / 64 residue K-tiles
#define KT_ALL 17        // + 1 tile for [e | s' | d' | 0]
#define WT_K 1088        // 1024 + 64

typedef __attribute__((ext_vector_type(8))) short short8;
typedef __attribute__((ext_vector_type(4))) short short4v;
typedef __attribute__((ext_vector_type(4))) float f32x4;

__device__ __forceinline__ short f2bf(float x) {
  union { float f; unsigned int u; } a; a.f = x;
  unsigned int r = a.u + 0x7FFFu + ((a.u >> 16) & 1u);
  return (short)(r >> 16);
}

// Build W' transposed as bf16: Wt[f][k'], k' in [0,1088).
// k'<1024 -> Wr[k'][f]; 1024+c: c<12 -> Wv[c][f]; c<24 -> Wsr[c-12][f];
// c<36 -> Wdr[c-24][f]; else 0.
__global__ void prep_wt_kernel(const float* __restrict__ Wv, const float* __restrict__ Wr,
                               const float* __restrict__ Wsr, const float* __restrict__ Wdr,
                               short* __restrict__ Wt) {
  int idx = blockIdx.x * 256 + threadIdx.x;
  if (idx >= FDIM * WT_K) return;
  int f = idx / WT_K;
  int k = idx - f * WT_K;
  float v = 0.0f;
  if (k < RDIM) v = Wr[k * FDIM + f];
  else {
    int c = k - RDIM;
    if (c < 12)      v = Wv[c * FDIM + f];
    else if (c < 24) v = Wsr[(c - 12) * FDIM + f];
    else if (c < 36) v = Wdr[(c - 24) * FDIM + f];
  }
  Wt[idx] = f2bf(v);
}

__global__ __launch_bounds__(256, 2)
void gnn_main_kernel(const float* __restrict__ atoms0, const float* __restrict__ resid0,
                     const int* __restrict__ same0, const int* __restrict__ diff0,
                     const float* __restrict__ atoms1, const float* __restrict__ resid1,
                     const int* __restrict__ same1, const int* __restrict__ diff1,
                     const short* __restrict__ Wt, float* __restrict__ out) {
  const int p = blockIdx.y;
  const float* atoms = p ? atoms1 : atoms0;
  const float* resid = p ? resid1 : resid0;
  const int*   same  = p ? same1  : same0;
  const int*   diff  = p ? diff1  : diff0;

  const size_t RES_SZ = (size_t)NATOMS * FDIM;   // 12,800,000
  const size_t IDX_SZ = (size_t)NATOMS * KNB;    //  1,000,000
  float* outRes  = out + (size_t)p * (RES_SZ + 2 * IDX_SZ);
  float* outSame = outRes + RES_SZ;
  float* outDiff = outSame + IDX_SZ;

  const int tid = threadIdx.x;
  const int m0 = blockIdx.x * BM;

  __shared__ short lA[BM * LDST];
  __shared__ short lB[BM * LDST];

  const int lane = tid & 63;
  const int wave = tid >> 6;
  const int wy = wave >> 1;   // row half (0/1)
  const int wx = wave & 1;    // col half (0/1)
  const int lc = lane & 15;
  const int lq = lane >> 4;

  f32x4 zero4 = {0.0f, 0.0f, 0.0f, 0.0f};
  f32x4 acc[4][4];
#pragma unroll
  for (int i = 0; i < 4; ++i)
#pragma unroll
    for (int j = 0; j < 4; ++j) acc[i][j] = zero4;

  const int kh = tid & 7;     // 8-bf16 chunk within 64-wide K tile
  const int r0 = tid >> 3;    // 0..31

  for (int kt = 0; kt < KT_ALL; ++kt) {
    if (kt < KT_RES) {
      // ---- stage A: residues fp32 -> bf16, rows m0..m0+127, cols kt*64..+64
#pragma unroll
      for (int pp = 0; pp < 4; ++pp) {
        int row = pp * 32 + r0;
        int gm = m0 + row;
        f32x4 v0 = zero4, v1 = zero4;
        if (gm < NATOMS) {
          const float* src = resid + (size_t)gm * RDIM + kt * BK + kh * 8;
          v0 = *(const f32x4*)src;
          v1 = *(const f32x4*)(src + 4);
        }
        short8 h = { f2bf(v0.x), f2bf(v0.y), f2bf(v0.z), f2bf(v0.w),
                     f2bf(v1.x), f2bf(v1.y), f2bf(v1.z), f2bf(v1.w) };
        *(short8*)(&lA[row * LDST + kh * 8]) = h;
      }
    } else {
      // ---- stage U tile: [e(12) | s'(12) | d'(12) | zeros(28)] per row,
      //      plus pass-through index outputs as floats.
      int ml = tid & 127;
      int gm = m0 + ml;
      bool isSame = tid < 128;
      const int* lst = isSame ? same : diff;
      float* oIdx = isSame ? outSame : outDiff;
      float s0=0,s1=0,s2=0,s3=0,s4=0,s5=0,s6=0,s7=0,s8=0,s9=0,s10=0,s11=0;
      int cnt = 0;
      if (gm < NATOMS) {
        const int* ip = lst + (size_t)gm * KNB;
        float* op = oIdx + (size_t)gm * KNB;
#pragma unroll
        for (int k = 0; k < KNB; ++k) {
          int idx = ip[k];
          op[k] = (float)idx;
          if (idx > -1) {
            ++cnt;
            const f32x4* rp = (const f32x4*)(atoms + (size_t)idx * ADIM);
            f32x4 a0 = rp[0], a1 = rp[1], a2 = rp[2];
            s0+=a0.x; s1+=a0.y; s2+=a0.z; s3+=a0.w;
            s4+=a1.x; s5+=a1.y; s6+=a1.z; s7+=a1.w;
            s8+=a2.x; s9+=a2.y; s10+=a2.z; s11+=a2.w;
          }
        }
      }
      float inv = 1.0f / (float)(cnt > 0 ? cnt : 1);
      int base = ml * LDST;
      if (isSame) {
        f32x4 e0 = zero4, e1 = zero4, e2 = zero4;
        if (gm < NATOMS) {
          const f32x4* ep = (const f32x4*)(atoms + (size_t)gm * ADIM);
          e0 = ep[0]; e1 = ep[1]; e2 = ep[2];
        }
        short8 he = { f2bf(e0.x), f2bf(e0.y), f2bf(e0.z), f2bf(e0.w),
                      f2bf(e1.x), f2bf(e1.y), f2bf(e1.z), f2bf(e1.w) };
        *(short8*)(&lA[base]) = he;
        short4v h2 = { f2bf(e2.x), f2bf(e2.y), f2bf(e2.z), f2bf(e2.w) };
        *(short4v*)(&lA[base + 8]) = h2;
        short4v hs0 = { f2bf(s0*inv), f2bf(s1*inv), f2bf(s2*inv),  f2bf(s3*inv)  };
        short4v hs1 = { f2bf(s4*inv), f2bf(s5*inv), f2bf(s6*inv),  f2bf(s7*inv)  };
        short4v hs2 = { f2bf(s8*inv), f2bf(s9*inv), f2bf(s10*inv), f2bf(s11*inv) };
        *(short4v*)(&lA[base + 12]) = hs0;
        *(short4v*)(&lA[base + 16]) = hs1;
        *(short4v*)(&lA[base + 20]) = hs2;
        short4v z = {0, 0, 0, 0};
        *(short4v*)(&lA[base + 36]) = z;
        *(short4v*)(&lA[base + 40]) = z;
        *(short4v*)(&lA[base + 44]) = z;
      } else {
        short4v hd0 = { f2bf(s0*inv), f2bf(s1*inv), f2bf(s2*inv),  f2bf(s3*inv)  };
        short4v hd1 = { f2bf(s4*inv), f2bf(s5*inv), f2bf(s6*inv),  f2bf(s7*inv)  };
        short4v hd2 = { f2bf(s8*inv), f2bf(s9*inv), f2bf(s10*inv), f2bf(s11*inv) };
        *(short4v*)(&lA[base + 24]) = hd0;
        *(short4v*)(&lA[base + 28]) = hd1;
        *(short4v*)(&lA[base + 32]) = hd2;
        short8 z8 = {0, 0, 0, 0, 0, 0, 0, 0};
        *(short8*)(&lA[base + 48]) = z8;
        *(short8*)(&lA[base + 56]) = z8;
      }
    }

    // ---- stage B: Wt (already bf16, f-major, k-contiguous) tile
#pragma unroll
    for (int pp = 0; pp < 4; ++pp) {
      int f = pp * 32 + r0;
      short8 w = *(const short8*)(Wt + (size_t)f * WT_K + kt * BK + kh * 8);
      *(short8*)(&lB[f * LDST + kh * 8]) = w;
    }

    __syncthreads();

    // ---- MFMA: 2 k-steps of 32
#pragma unroll
    for (int s = 0; s < 2; ++s) {
      int ko = s * 32 + lq * 8;
      short8 af[4], bfr[4];
#pragma unroll
      for (int i = 0; i < 4; ++i)
        af[i] = *(const short8*)(&lA[(wy * 64 + i * 16 + lc) * LDST + ko]);
#pragma unroll
      for (int j = 0; j < 4; ++j)
        bfr[j] = *(const short8*)(&lB[(wx * 64 + j * 16 + lc) * LDST + ko]);
#pragma unroll
      for (int i = 0; i < 4; ++i)
#pragma unroll
        for (int j = 0; j < 4; ++j)
          acc[i][j] = __builtin_amdgcn_mfma_f32_16x16x32_bf16(af[i], bfr[j], acc[i][j], 0, 0, 0);
    }

    __syncthreads();
  }

  // ---- epilogue: relu + store (C/D layout: col=lane&15, row=quad*4+reg)
#pragma unroll
  for (int i = 0; i < 4; ++i) {
#pragma unroll
    for (int j = 0; j < 4; ++j) {
      int f = wx * 64 + j * 16 + lc;
#pragma unroll
      for (int r = 0; r < 4; ++r) {
        int m = m0 + wy * 64 + i * 16 + lq * 4 + r;
        if (m < NATOMS)
          outRes[(size_t)m * FDIM + f] = fmaxf(acc[i][j][r], 0.0f);
      }
    }
  }
}

extern "C" void kernel_launch(void* const* d_in, const int* in_sizes, int n_in,
                              void* d_out, int out_size, void* d_ws, size_t ws_size,
                              hipStream_t stream) {
  const float* atoms0    = (const float*)d_in[0];
  const float* residues0 = (const float*)d_in[1];
  const int*   same0     = (const int*)d_in[2];
  const int*   diff0     = (const int*)d_in[3];
  const float* atoms1    = (const float*)d_in[4];
  const float* residues1 = (const float*)d_in[5];
  const int*   same1     = (const int*)d_in[6];
  const int*   diff1     = (const int*)d_in[7];
  const float* Wv        = (const float*)d_in[8];
  const float* Wr        = (const float*)d_in[9];
  const float* Wsr       = (const float*)d_in[10];
  const float* Wdr       = (const float*)d_in[11];

  short* Wt = (short*)d_ws;  // 128*1088*2 = 278,528 B

  int prepElems = FDIM * WT_K;
  prep_wt_kernel<<<(prepElems + 255) / 256, 256, 0, stream>>>(Wv, Wr, Wsr, Wdr, Wt);

  dim3 grid((NATOMS + BM - 1) / BM, 2);
  gnn_main_kernel<<<grid, 256, 0, stream>>>(atoms0, residues0, same0, diff0,
                                            atoms1, residues1, same1, diff1,
                                            Wt, (float*)d_out);
}